// Round 11
// baseline (110.863 us; speedup 1.0000x reference)
//
#include <hip/hip_runtime.h>
#include <math.h>

#define TPB   256
#define SL    16             // per-thread segment length
#define SEGS  65536          // TLEN / SL (per row)
#define TLEN  1048576
#define MOFF  4065           // 65047 / 16
#define ROFF  7              // 65047 % 16
#define NEMA  4              // 0: short/pred, 1: short/targ, 2: long/pred, 3: long/targ
#define RPT   256            // segs per thread in pass 2 (SEGS / TPB)

__device__ __forceinline__ float comp(const float4& v, int m) {
    return m == 0 ? v.x : m == 1 ? v.y : m == 2 ? v.z : v.w;
}

// integer power by repeated squaring, deterministic
__device__ __forceinline__ float ipowf(float base, int e) {
    float r = 1.0f, p = base;
    while (e) { if (e & 1) r *= p; p *= p; e >>= 1; }
    return r;
}

// Pass 1: per-16-sample-segment UNSCALED EMA aggregates, 4-lane cooperative.
// Lane i of a wave reads float4 #i of a contiguous 1KB span (fully coalesced);
// group of 4 lanes = one segment. Segment aggregate via the weighted-sum
// identity: sum_e am^(15-e) x_e = sum_g A4^(3-g) * b_g  (b_g = quad EMA agg).
__global__ __launch_bounds__(TPB) void ldr_partials(
    const float* __restrict__ pred, const float* __restrict__ targ,
    float amS, float amL, float A4S, float A4L,
    float* __restrict__ pB, int rows)
{
    const int j = threadIdx.x, lane = j & 63, w = j >> 6;
    const int g = lane & 3;
    const size_t plane = (size_t)rows * SEGS;
    // block covers 256 segments: wave w covers segs [b*256+w*64, +64), 4 iters
    const int segw = blockIdx.x * 256 + w * 64;       // wave's first segment
    const float wS = ipowf(A4S, 3 - g);
    const float wL = ipowf(A4L, 3 - g);
    const float4* P4 = (const float4*)pred;
    const float4* T4 = (const float4*)targ;

    #pragma unroll
    for (int it = 0; it < 4; ++it) {
        const int s0 = segw + it * 16;                // first seg of this iter
        const size_t q0 = (size_t)s0 * 4 + lane;      // global float4 index
        float4 u = P4[q0];
        float4 v = T4[q0];
        // quad-local unscaled EMA aggregates
        float bSP = u.x, bLP = u.x, bST = v.x, bLT = v.x;
        #pragma unroll
        for (int mm = 1; mm < 4; ++mm) {
            float xu = comp(u, mm), xv = comp(v, mm);
            bSP = fmaf(amS, bSP, xu); bLP = fmaf(amL, bLP, xu);
            bST = fmaf(amS, bST, xv); bLT = fmaf(amL, bLT, xv);
        }
        bSP *= wS; bST *= wS; bLP *= wL; bLT *= wL;
        // sum within the 4-lane group (all 4 lanes end with all 4 sums)
        bSP += __shfl_xor(bSP, 1, 64); bSP += __shfl_xor(bSP, 2, 64);
        bST += __shfl_xor(bST, 1, 64); bST += __shfl_xor(bST, 2, 64);
        bLP += __shfl_xor(bLP, 1, 64); bLP += __shfl_xor(bLP, 2, 64);
        bLT += __shfl_xor(bLT, 1, 64); bLT += __shfl_xor(bLT, 2, 64);
        // lane g writes plane g for its segment -> 16-dword dense bursts
        const int seg = s0 + (lane >> 2);
        float val = (g == 0) ? bSP : (g == 1) ? bST : (g == 2) ? bLP : bLT;
        pB[(size_t)g * plane + seg] = val;
    }
}

// Pass 2: carry-in per segment, in-place. One 256-thread block per (E,r)
// plane; thread j owns RPT consecutive aggregates, processed as 4 interleaved
// chains of 64 (ILP-4) combined with Ac^64 weights.
__global__ __launch_bounds__(TPB) void ldr_carry(
    float* __restrict__ pB,
    float AcS, float AcST, float AcSW,
    float AcL, float AcLT, float AcLW, int rows)
{
    __shared__ float slots[4];
    const int g = blockIdx.x;               // E*rows + r
    const int j = threadIdx.x, lane = j & 63, w = j >> 6;
    const bool isShort = g < 2 * rows;
    const float Ac  = isShort ? AcS  : AcL;     // am^SL
    const float AcT = isShort ? AcST : AcLT;    // am^(SL*RPT)
    const float AcW = isShort ? AcSW : AcLW;    // am^(SL*RPT*64)
    const float A64 = ipowf(Ac, 64);            // am^(SL*64)
    float* Bv = pB + (size_t)g * SEGS + (size_t)j * RPT;

    // sweep 1: 4 interleaved chains of 64
    float Bc[4] = {0.f, 0.f, 0.f, 0.f};
    for (int mm = 0; mm < 64; ++mm) {
        #pragma unroll
        for (int c = 0; c < 4; ++c)
            Bc[c] = fmaf(Ac, Bc[c], Bv[c * 64 + mm]);
    }
    float B = Bc[0];
    B = fmaf(A64, B, Bc[1]);
    B = fmaf(A64, B, Bc[2]);
    B = fmaf(A64, B, Bc[3]);

    // wave scan over thread aggregates, constant multiplier AcT
    float incl = B, Ad = AcT;
    #pragma unroll
    for (int d = 1; d < 64; d <<= 1) {
        float pb = __shfl_up(incl, d, 64);
        if (lane >= d) incl = fmaf(Ad, pb, incl);
        Ad *= Ad;
    }
    float ex = __shfl_up(incl, 1, 64);
    if (lane == 0) ex = 0.f;
    if (lane == 63) slots[w] = incl;
    __syncthreads();
    float Wc = 0.f;
    for (int u = 0; u < w; ++u) Wc = fmaf(Wc, AcW, slots[u]);
    float carry = fmaf(ipowf(AcT, lane), Wc, ex);

    // chain-start carries: c_{k+1} = A64 * c_k + Bc_k
    float cc[4];
    cc[0] = carry;
    cc[1] = fmaf(A64, cc[0], Bc[0]);
    cc[2] = fmaf(A64, cc[1], Bc[1]);
    cc[3] = fmaf(A64, cc[2], Bc[2]);

    // sweep 2: 4 interleaved chains, read old aggregate, write carry
    for (int mm = 0; mm < 64; ++mm) {
        #pragma unroll
        for (int c = 0; c < 4; ++c) {
            float old = Bv[c * 64 + mm];
            Bv[c * 64 + mm] = cc[c];
            cc[c] = fmaf(Ac, cc[c], old);
        }
    }
}

// Pass 3: fully thread-independent fused loss (unchanged from R10).
__global__ __launch_bounds__(TPB) void ldr_loss(
    const float* __restrict__ pred, const float* __restrict__ targ,
    const float* __restrict__ cin,
    float amS, float amL, float* __restrict__ partial, int rows)
{
    const int tid = blockIdx.x * TPB + threadIdx.x;
    const int lane = threadIdx.x & 63;
    const int r = tid >> 16, m = tid & (SEGS - 1);
    const int a = (m + MOFF) & (SEGS - 1);
    const int b = (m + MOFF + 1) & (SEGS - 1);
    const float* P = pred + (size_t)r * TLEN;
    const float* T = targ + (size_t)r * TLEN;
    const size_t plane = (size_t)rows * SEGS;
    const size_t rbase = (size_t)r * SEGS;

    float sp[SL], st[SL];
    {
        const float4* Sp4 = (const float4*)(P + (size_t)m * SL);
        const float4* St4 = (const float4*)(T + (size_t)m * SL);
        float ysp = cin[0 * plane + rbase + m];
        float yst = cin[1 * plane + rbase + m];
        #pragma unroll
        for (int q = 0; q < SL / 4; ++q) {
            float4 u = Sp4[q], v = St4[q];
            #pragma unroll
            for (int mm = 0; mm < 4; ++mm) {
                ysp = fmaf(amS, ysp, comp(u, mm)); sp[4 * q + mm] = ysp;
                yst = fmaf(amS, yst, comp(v, mm)); st[4 * q + mm] = yst;
            }
        }
    }

    float ylp = cin[2 * plane + rbase + a];
    float ylt = cin[3 * plane + rbase + a];
    const float4* Ap4 = (const float4*)(P + (size_t)a * SL);
    const float4* At4 = (const float4*)(T + (size_t)a * SL);
    const float4* Bp4 = (const float4*)(P + (size_t)b * SL);
    const float4* Bt4 = (const float4*)(T + (size_t)b * SL);

    float lsum = 0.f;
    #pragma unroll
    for (int q = 0; q < SL / 4; ++q) {
        float4 u = Ap4[q], v = At4[q];
        #pragma unroll
        for (int mm = 0; mm < 4; ++mm) {
            const int e = 4 * q + mm;
            ylp = fmaf(amL, ylp, comp(u, mm));
            ylt = fmaf(amL, ylt, comp(v, mm));
            if (e >= ROFF) {
                const int i = e - ROFF;
                lsum += fabsf(__logf(__fdividef(sp[i] * ylt, st[i] * ylp)));
            }
        }
    }
    #pragma unroll
    for (int q = 0; q < 2; ++q) {
        float4 u = Bp4[q], v = Bt4[q];
        #pragma unroll
        for (int mm = 0; mm < 4; ++mm) {
            const int e = 4 * q + mm;
            if (e < ROFF) {
                ylp = fmaf(amL, ylp, comp(u, mm));
                ylt = fmaf(amL, ylt, comp(v, mm));
                const int i = e + (SL - ROFF);
                lsum += fabsf(__logf(__fdividef(sp[i] * ylt, st[i] * ylp)));
            }
        }
    }

    #pragma unroll
    for (int d = 32; d > 0; d >>= 1) lsum += __shfl_xor(lsum, d, 64);
    if (lane == 0) partial[tid >> 6] = lsum;
}

__global__ void ldr_finalize(const float* __restrict__ partial, int nparts,
                             float* __restrict__ out, double inv_n)
{
    __shared__ double sd[256];
    double s = 0.0;
    for (int i = threadIdx.x; i < nparts; i += 256) s += (double)partial[i];
    sd[threadIdx.x] = s;
    __syncthreads();
    for (int d = 128; d > 0; d >>= 1) {
        if (threadIdx.x < d) sd[threadIdx.x] += sd[threadIdx.x + d];
        __syncthreads();
    }
    if (threadIdx.x == 0) out[0] = (float)(sd[0] * inv_n);
}

extern "C" void kernel_launch(void* const* d_in, const int* in_sizes, int n_in,
                              void* d_out, int out_size, void* d_ws, size_t ws_size,
                              hipStream_t stream)
{
    const float* pred = (const float*)d_in[0];
    const float* targ = (const float*)d_in[1];
    const int n = in_sizes[0];
    const int rows = n / TLEN;   // 16

    const double csd = 1.0 - exp(-2200.0 / (50.0 * 44100.0));
    const double cld = 1.0 - exp(-2200.0 / (3000.0 * 44100.0));
    const double amSd = 1.0 - csd, amLd = 1.0 - cld;
    const float amS = (float)amSd, amL = (float)amLd;
    const float A4S  = (float)pow(amSd, 4.0);
    const float A4L  = (float)pow(amLd, 4.0);
    const float AcS  = (float)pow(amSd, (double)SL);
    const float AcST = (float)pow(amSd, (double)SL * RPT);
    const float AcSW = (float)pow(amSd, (double)SL * RPT * 64.0);
    const float AcL  = (float)pow(amLd, (double)SL);
    const float AcLT = (float)pow(amLd, (double)SL * RPT);
    const float AcLW = (float)pow(amLd, (double)SL * RPT * 64.0);

    // ws layout: [0,256): reserved; pB = NEMA*rows*SEGS floats (16.8 MB for
    // rows=16), becomes the carry-in table in-place; then partial floats.
    char* wsb = (char*)d_ws;
    float* pB      = (float*)(wsb + 256);
    float* partial = pB + (size_t)NEMA * rows * SEGS;

    const int nthreads = rows * SEGS;          // 1048576
    const int nblocks  = nthreads / TPB;       // 4096
    const int nparts   = nthreads / 64;        // 16384

    ldr_partials<<<nblocks, TPB, 0, stream>>>(pred, targ, amS, amL,
                                              A4S, A4L, pB, rows);
    ldr_carry<<<NEMA * rows, TPB, 0, stream>>>(pB, AcS, AcST, AcSW,
                                               AcL, AcLT, AcLW, rows);
    ldr_loss<<<nblocks, TPB, 0, stream>>>(pred, targ, pB, amS, amL, partial, rows);

    const double inv_n = 1.0 / ((double)rows * (double)TLEN);
    ldr_finalize<<<1, 256, 0, stream>>>(partial, nparts, (float*)d_out, inv_n);
}

// Round 12
// 90.019 us; speedup vs baseline: 1.2315x; 1.2315x over previous
//
#include <hip/hip_runtime.h>
#include <math.h>

#define TPB   256
#define SL    16             // per-segment length
#define SEGS  65536          // TLEN / SL (per row)
#define PAIRS 32768          // SEGS/2 (pass-1 thread = 2 segments)
#define TLEN  1048576
#define MOFF  4065           // 65047 / 16
#define ROFF  7              // 65047 % 16
#define NEMA  4              // 0: short/pred, 1: short/targ, 2: long/pred, 3: long/targ
#define TILE  1024           // segments per scan tile (256 threads * 4)
#define NTILE 64             // SEGS / TILE

__device__ __forceinline__ float comp(const float4& v, int m) {
    return m == 0 ? v.x : m == 1 ? v.y : m == 2 ? v.z : v.w;
}

__device__ __forceinline__ float ipowf(float base, int e) {
    float r = 1.0f, p = base;
    while (e) { if (e & 1) r *= p; p *= p; e >>= 1; }
    return r;
}

// Pass 1: per-16-sample-segment UNSCALED EMA aggregates. 2 segments/thread;
// ALL 16 float4 loads issued before the asm fence (forces load batching —
// R11's VGPR=12 serialization was 8 x ~500cyc latency exposures per thread).
__global__ __launch_bounds__(TPB, 4) void ldr_partials(
    const float* __restrict__ pred, const float* __restrict__ targ,
    float amS, float amL, float* __restrict__ pB, int rows)
{
    const int tid = blockIdx.x * TPB + threadIdx.x;
    const int r = tid / PAIRS;
    const int p = tid & (PAIRS - 1);
    const size_t base = (size_t)r * TLEN + (size_t)p * 32;
    const float4* P4 = (const float4*)(pred + base);
    const float4* T4 = (const float4*)(targ + base);
    float4 u[8], v[8];
    #pragma unroll
    for (int q = 0; q < 8; ++q) u[q] = P4[q];
    #pragma unroll
    for (int q = 0; q < 8; ++q) v[q] = T4[q];
    asm volatile("" ::: "memory");   // loads may not sink below this

    float res[NEMA][2];
    #pragma unroll
    for (int sg = 0; sg < 2; ++sg) {
        float sp = 0.f, st = 0.f, lp = 0.f, lt = 0.f;
        #pragma unroll
        for (int q = 0; q < 4; ++q) {
            float4 uu = u[sg * 4 + q], vv = v[sg * 4 + q];
            #pragma unroll
            for (int mm = 0; mm < 4; ++mm) {
                float xu = comp(uu, mm), xv = comp(vv, mm);
                sp = fmaf(amS, sp, xu); lp = fmaf(amL, lp, xu);
                st = fmaf(amS, st, xv); lt = fmaf(amL, lt, xv);
            }
        }
        res[0][sg] = sp; res[1][sg] = st; res[2][sg] = lp; res[3][sg] = lt;
    }
    const size_t plane = (size_t)rows * SEGS;
    const size_t idx = (size_t)r * SEGS + 2 * (size_t)p;
    #pragma unroll
    for (int E = 0; E < NEMA; ++E)
        *(float2*)(pB + E * plane + idx) = make_float2(res[E][0], res[E][1]);
}

// Pass 2a: per-tile (1024-segment) aggregates. Coalesced float4 reads.
__global__ __launch_bounds__(TPB) void ldr_tile_agg(
    const float* __restrict__ pB, float* __restrict__ tA,
    float AcS, float AcL, int rows)
{
    __shared__ float slots[4];
    const int t = blockIdx.x, g = blockIdx.y;
    const int j = threadIdx.x, lane = j & 63, w = j >> 6;
    const float Ac = (g < 2 * rows) ? AcS : AcL;       // am^SL
    const float Ac4 = (Ac * Ac) * (Ac * Ac);
    const float4 E = *(const float4*)(pB + (size_t)g * SEGS
                                      + (size_t)t * TILE + (size_t)j * 4);
    float B = E.x;
    B = fmaf(Ac, B, E.y); B = fmaf(Ac, B, E.z); B = fmaf(Ac, B, E.w);
    float incl = B, Ad = Ac4;
    #pragma unroll
    for (int d = 1; d < 64; d <<= 1) {
        float pb = __shfl_up(incl, d, 64);
        if (lane >= d) incl = fmaf(Ad, pb, incl);
        Ad *= Ad;
    }
    if (lane == 63) slots[w] = incl;
    __syncthreads();
    if (j == 0) {
        const float Ac256 = ipowf(Ac4, 64);
        float T = slots[0];
        T = fmaf(Ac256, T, slots[1]);
        T = fmaf(Ac256, T, slots[2]);
        T = fmaf(Ac256, T, slots[3]);
        tA[g * NTILE + t] = T;
    }
}

// Pass 2b: per-plane scan of the 64 tile aggregates -> tile carry-ins.
__global__ __launch_bounds__(64) void ldr_tile_scan(
    const float* __restrict__ tA, float* __restrict__ tC,
    float AtS, float AtL, int rows)
{
    const int g = blockIdx.x, lane = threadIdx.x;
    const float A = (g < 2 * rows) ? AtS : AtL;        // am^(SL*TILE)
    float incl = tA[g * NTILE + lane], Ad = A;
    #pragma unroll
    for (int d = 1; d < 64; d <<= 1) {
        float pb = __shfl_up(incl, d, 64);
        if (lane >= d) incl = fmaf(Ad, pb, incl);
        Ad *= Ad;
    }
    float ex = __shfl_up(incl, 1, 64);
    if (lane == 0) ex = 0.f;
    tC[g * NTILE + lane] = ex;
}

// Pass 2c: convert aggregates -> per-segment carry-ins, in place, coalesced.
__global__ __launch_bounds__(TPB) void ldr_carry_fill(
    float* __restrict__ pB, const float* __restrict__ tC,
    float AcS, float AcL, float Ac256S, float Ac256L, int rows)
{
    __shared__ float slots[4];
    const int t = blockIdx.x, g = blockIdx.y;
    const int j = threadIdx.x, lane = j & 63, w = j >> 6;
    const bool isShort = g < 2 * rows;
    const float Ac    = isShort ? AcS : AcL;
    const float Ac4   = (Ac * Ac) * (Ac * Ac);
    const float Ac256 = isShort ? Ac256S : Ac256L;     // am^(SL*256)
    float* ptr = pB + (size_t)g * SEGS + (size_t)t * TILE + (size_t)j * 4;
    const float4 E = *(const float4*)ptr;
    float B = E.x;
    B = fmaf(Ac, B, E.y); B = fmaf(Ac, B, E.z); B = fmaf(Ac, B, E.w);
    float incl = B, Ad = Ac4;
    #pragma unroll
    for (int d = 1; d < 64; d <<= 1) {
        float pb = __shfl_up(incl, d, 64);
        if (lane >= d) incl = fmaf(Ad, pb, incl);
        Ad *= Ad;
    }
    float ex = __shfl_up(incl, 1, 64);
    if (lane == 0) ex = 0.f;
    if (lane == 63) slots[w] = incl;
    __syncthreads();
    // acc = Ac256^w * C_tile + sum_{u<w} slots[u]*Ac256^(w-1-u)
    float acc = tC[g * NTILE + t];
    for (int u = 0; u < w; ++u) acc = fmaf(acc, Ac256, slots[u]);
    float carry = fmaf(ipowf(Ac4, lane), acc, ex);
    float4 out;
    out.x = carry; carry = fmaf(Ac, carry, E.x);
    out.y = carry; carry = fmaf(Ac, carry, E.y);
    out.z = carry; carry = fmaf(Ac, carry, E.z);
    out.w = carry;
    *(float4*)ptr = out;
}

// Pass 3: fully thread-independent fused loss (compute unchanged from R10);
// adds in-block reduction -> one partial per block.
__global__ __launch_bounds__(TPB) void ldr_loss(
    const float* __restrict__ pred, const float* __restrict__ targ,
    const float* __restrict__ cin,
    float amS, float amL, float* __restrict__ partial, int rows)
{
    __shared__ float rs[4];
    const int tid = blockIdx.x * TPB + threadIdx.x;
    const int lane = threadIdx.x & 63, w = threadIdx.x >> 6;
    const int r = tid >> 16, m = tid & (SEGS - 1);
    const int a = (m + MOFF) & (SEGS - 1);
    const int b = (m + MOFF + 1) & (SEGS - 1);
    const float* P = pred + (size_t)r * TLEN;
    const float* T = targ + (size_t)r * TLEN;
    const size_t plane = (size_t)rows * SEGS;
    const size_t rbase = (size_t)r * SEGS;

    float sp[SL], st[SL];
    {
        const float4* Sp4 = (const float4*)(P + (size_t)m * SL);
        const float4* St4 = (const float4*)(T + (size_t)m * SL);
        float ysp = cin[0 * plane + rbase + m];
        float yst = cin[1 * plane + rbase + m];
        #pragma unroll
        for (int q = 0; q < SL / 4; ++q) {
            float4 u = Sp4[q], v = St4[q];
            #pragma unroll
            for (int mm = 0; mm < 4; ++mm) {
                ysp = fmaf(amS, ysp, comp(u, mm)); sp[4 * q + mm] = ysp;
                yst = fmaf(amS, yst, comp(v, mm)); st[4 * q + mm] = yst;
            }
        }
    }

    float ylp = cin[2 * plane + rbase + a];
    float ylt = cin[3 * plane + rbase + a];
    const float4* Ap4 = (const float4*)(P + (size_t)a * SL);
    const float4* At4 = (const float4*)(T + (size_t)a * SL);
    const float4* Bp4 = (const float4*)(P + (size_t)b * SL);
    const float4* Bt4 = (const float4*)(T + (size_t)b * SL);

    float lsum = 0.f;
    #pragma unroll
    for (int q = 0; q < SL / 4; ++q) {
        float4 u = Ap4[q], v = At4[q];
        #pragma unroll
        for (int mm = 0; mm < 4; ++mm) {
            const int e = 4 * q + mm;
            ylp = fmaf(amL, ylp, comp(u, mm));
            ylt = fmaf(amL, ylt, comp(v, mm));
            if (e >= ROFF) {
                const int i = e - ROFF;
                lsum += fabsf(__logf(__fdividef(sp[i] * ylt, st[i] * ylp)));
            }
        }
    }
    #pragma unroll
    for (int q = 0; q < 2; ++q) {
        float4 u = Bp4[q], v = Bt4[q];
        #pragma unroll
        for (int mm = 0; mm < 4; ++mm) {
            const int e = 4 * q + mm;
            if (e < ROFF) {
                ylp = fmaf(amL, ylp, comp(u, mm));
                ylt = fmaf(amL, ylt, comp(v, mm));
                const int i = e + (SL - ROFF);
                lsum += fabsf(__logf(__fdividef(sp[i] * ylt, st[i] * ylp)));
            }
        }
    }

    #pragma unroll
    for (int d = 32; d > 0; d >>= 1) lsum += __shfl_xor(lsum, d, 64);
    if (lane == 0) rs[w] = lsum;
    __syncthreads();
    if (threadIdx.x == 0)
        partial[blockIdx.x] = rs[0] + rs[1] + rs[2] + rs[3];
}

__global__ void ldr_finalize(const float* __restrict__ partial, int nparts,
                             float* __restrict__ out, double inv_n)
{
    __shared__ double sd[256];
    double s = 0.0;
    for (int i = threadIdx.x; i < nparts; i += 256) s += (double)partial[i];
    sd[threadIdx.x] = s;
    __syncthreads();
    for (int d = 128; d > 0; d >>= 1) {
        if (threadIdx.x < d) sd[threadIdx.x] += sd[threadIdx.x + d];
        __syncthreads();
    }
    if (threadIdx.x == 0) out[0] = (float)(sd[0] * inv_n);
}

extern "C" void kernel_launch(void* const* d_in, const int* in_sizes, int n_in,
                              void* d_out, int out_size, void* d_ws, size_t ws_size,
                              hipStream_t stream)
{
    const float* pred = (const float*)d_in[0];
    const float* targ = (const float*)d_in[1];
    const int n = in_sizes[0];
    const int rows = n / TLEN;   // 16

    const double csd = 1.0 - exp(-2200.0 / (50.0 * 44100.0));
    const double cld = 1.0 - exp(-2200.0 / (3000.0 * 44100.0));
    const double amSd = 1.0 - csd, amLd = 1.0 - cld;
    const float amS = (float)amSd, amL = (float)amLd;
    const float AcS    = (float)pow(amSd, 16.0);       // per segment
    const float AcL    = (float)pow(amLd, 16.0);
    const float Ac256S = (float)pow(amSd, 16.0 * 256); // per 256 segments
    const float Ac256L = (float)pow(amLd, 16.0 * 256);
    const float AtS    = (float)pow(amSd, 16.0 * TILE); // per tile
    const float AtL    = (float)pow(amLd, 16.0 * TILE);

    // ws: [0,256) reserved; pB (NEMA*rows*SEGS floats = 16.8 MB; aggregates,
    // overwritten in-place with carry-ins by 2c); partial (4096 f);
    // tA (64*64 f); tC (64*64 f).
    char* wsb = (char*)d_ws;
    float* pB      = (float*)(wsb + 256);
    float* partial = pB + (size_t)NEMA * rows * SEGS;
    float* tA      = partial + 4096;
    float* tC      = tA + NEMA * 16 * NTILE;

    const int nthreads = rows * SEGS;              // 1048576
    const int nblocksL = nthreads / TPB;           // 4096 (loss)
    const int nblocksP = rows * PAIRS / TPB;       // 2048 (partials)
    const int nplanes  = NEMA * rows;              // 64

    ldr_partials<<<nblocksP, TPB, 0, stream>>>(pred, targ, amS, amL, pB, rows);
    dim3 gridT(NTILE, nplanes);
    ldr_tile_agg<<<gridT, TPB, 0, stream>>>(pB, tA, AcS, AcL, rows);
    ldr_tile_scan<<<nplanes, 64, 0, stream>>>(tA, tC, AtS, AtL, rows);
    ldr_carry_fill<<<gridT, TPB, 0, stream>>>(pB, tC, AcS, AcL,
                                              Ac256S, Ac256L, rows);
    ldr_loss<<<nblocksL, TPB, 0, stream>>>(pred, targ, pB, amS, amL,
                                           partial, rows);

    const double inv_n = 1.0 / ((double)rows * (double)TLEN);
    ldr_finalize<<<1, 256, 0, stream>>>(partial, nblocksL, (float*)d_out, inv_n);
}

// Round 13
// 80.344 us; speedup vs baseline: 1.3799x; 1.1204x over previous
//
#include <hip/hip_runtime.h>
#include <math.h>

#define TPB   256
#define SL    16             // per-segment length
#define SEGS  65536          // TLEN / SL (per row)
#define PAIRS 32768          // SEGS/2 (pass-1 thread = 2 segments)
#define TLEN  1048576
#define MOFF  4065           // 65047 / 16
#define ROFF  7              // 65047 % 16
#define NEMA  4              // 0: short/pred, 1: short/targ, 2: long/pred, 3: long/targ
#define TILE  1024           // segments per scan tile (256 threads * 4)
#define NTILE 64             // SEGS / TILE

__device__ __forceinline__ float comp(const float4& v, int m) {
    return m == 0 ? v.x : m == 1 ? v.y : m == 2 ? v.z : v.w;
}

__device__ __forceinline__ float ipowf(float base, int e) {
    float r = 1.0f, p = base;
    while (e) { if (e & 1) r *= p; p *= p; e >>= 1; }
    return r;
}

// Pass 1: per-16-sample-segment UNSCALED EMA aggregates. 2 segments/thread.
// ALL 16 float4 loads issued, then sched_barrier(0): unlike a "memory"
// clobber, it stops REGISTER-ONLY fmas from being hoisted between loads
// (rule #18) -> one latency exposure per thread instead of four.
__global__ __launch_bounds__(TPB, 4) void ldr_partials(
    const float* __restrict__ pred, const float* __restrict__ targ,
    float amS, float amL, float* __restrict__ pB, int rows)
{
    const int tid = blockIdx.x * TPB + threadIdx.x;
    const int r = tid / PAIRS;
    const int p = tid & (PAIRS - 1);
    const size_t base = (size_t)r * TLEN + (size_t)p * 32;
    const float4* P4 = (const float4*)(pred + base);
    const float4* T4 = (const float4*)(targ + base);
    float4 u[8], v[8];
    #pragma unroll
    for (int q = 0; q < 8; ++q) u[q] = P4[q];
    #pragma unroll
    for (int q = 0; q < 8; ++q) v[q] = T4[q];
    __builtin_amdgcn_sched_barrier(0);   // nothing crosses: loads all issue first

    float res[NEMA][2];
    #pragma unroll
    for (int sg = 0; sg < 2; ++sg) {
        float sp = 0.f, st = 0.f, lp = 0.f, lt = 0.f;
        #pragma unroll
        for (int q = 0; q < 4; ++q) {
            float4 uu = u[sg * 4 + q], vv = v[sg * 4 + q];
            #pragma unroll
            for (int mm = 0; mm < 4; ++mm) {
                float xu = comp(uu, mm), xv = comp(vv, mm);
                sp = fmaf(amS, sp, xu); lp = fmaf(amL, lp, xu);
                st = fmaf(amS, st, xv); lt = fmaf(amL, lt, xv);
            }
        }
        res[0][sg] = sp; res[1][sg] = st; res[2][sg] = lp; res[3][sg] = lt;
    }
    const size_t plane = (size_t)rows * SEGS;
    const size_t idx = (size_t)r * SEGS + 2 * (size_t)p;
    #pragma unroll
    for (int E = 0; E < NEMA; ++E)
        *(float2*)(pB + E * plane + idx) = make_float2(res[E][0], res[E][1]);
}

// Pass 2a: per-tile (1024-segment) aggregates. Coalesced float4 reads.
__global__ __launch_bounds__(TPB) void ldr_tile_agg(
    const float* __restrict__ pB, float* __restrict__ tA,
    float AcS, float AcL, int rows)
{
    __shared__ float slots[4];
    const int t = blockIdx.x, g = blockIdx.y;
    const int j = threadIdx.x, lane = j & 63, w = j >> 6;
    const float Ac = (g < 2 * rows) ? AcS : AcL;       // am^SL
    const float Ac4 = (Ac * Ac) * (Ac * Ac);
    const float4 E = *(const float4*)(pB + (size_t)g * SEGS
                                      + (size_t)t * TILE + (size_t)j * 4);
    float B = E.x;
    B = fmaf(Ac, B, E.y); B = fmaf(Ac, B, E.z); B = fmaf(Ac, B, E.w);
    float incl = B, Ad = Ac4;
    #pragma unroll
    for (int d = 1; d < 64; d <<= 1) {
        float pb = __shfl_up(incl, d, 64);
        if (lane >= d) incl = fmaf(Ad, pb, incl);
        Ad *= Ad;
    }
    if (lane == 63) slots[w] = incl;
    __syncthreads();
    if (j == 0) {
        const float Ac256 = ipowf(Ac4, 64);
        float T = slots[0];
        T = fmaf(Ac256, T, slots[1]);
        T = fmaf(Ac256, T, slots[2]);
        T = fmaf(Ac256, T, slots[3]);
        tA[g * NTILE + t] = T;
    }
}

// Pass 2b: per-plane scan of the 64 tile aggregates -> tile carry-ins.
__global__ __launch_bounds__(64) void ldr_tile_scan(
    const float* __restrict__ tA, float* __restrict__ tC,
    float AtS, float AtL, int rows)
{
    const int g = blockIdx.x, lane = threadIdx.x;
    const float A = (g < 2 * rows) ? AtS : AtL;        // am^(SL*TILE)
    float incl = tA[g * NTILE + lane], Ad = A;
    #pragma unroll
    for (int d = 1; d < 64; d <<= 1) {
        float pb = __shfl_up(incl, d, 64);
        if (lane >= d) incl = fmaf(Ad, pb, incl);
        Ad *= Ad;
    }
    float ex = __shfl_up(incl, 1, 64);
    if (lane == 0) ex = 0.f;
    tC[g * NTILE + lane] = ex;
}

// Pass 2c: convert aggregates -> per-segment carry-ins, in place, coalesced.
__global__ __launch_bounds__(TPB) void ldr_carry_fill(
    float* __restrict__ pB, const float* __restrict__ tC,
    float AcS, float AcL, float Ac256S, float Ac256L, int rows)
{
    __shared__ float slots[4];
    const int t = blockIdx.x, g = blockIdx.y;
    const int j = threadIdx.x, lane = j & 63, w = j >> 6;
    const bool isShort = g < 2 * rows;
    const float Ac    = isShort ? AcS : AcL;
    const float Ac4   = (Ac * Ac) * (Ac * Ac);
    const float Ac256 = isShort ? Ac256S : Ac256L;     // am^(SL*256)
    float* ptr = pB + (size_t)g * SEGS + (size_t)t * TILE + (size_t)j * 4;
    const float4 E = *(const float4*)ptr;
    float B = E.x;
    B = fmaf(Ac, B, E.y); B = fmaf(Ac, B, E.z); B = fmaf(Ac, B, E.w);
    float incl = B, Ad = Ac4;
    #pragma unroll
    for (int d = 1; d < 64; d <<= 1) {
        float pb = __shfl_up(incl, d, 64);
        if (lane >= d) incl = fmaf(Ad, pb, incl);
        Ad *= Ad;
    }
    float ex = __shfl_up(incl, 1, 64);
    if (lane == 0) ex = 0.f;
    if (lane == 63) slots[w] = incl;
    __syncthreads();
    float acc = tC[g * NTILE + t];
    for (int u = 0; u < w; ++u) acc = fmaf(acc, Ac256, slots[u]);
    float carry = fmaf(ipowf(Ac4, lane), acc, ex);
    float4 out;
    out.x = carry; carry = fmaf(Ac, carry, E.x);
    out.y = carry; carry = fmaf(Ac, carry, E.y);
    out.z = carry; carry = fmaf(Ac, carry, E.z);
    out.w = carry;
    *(float4*)ptr = out;
}

// Pass 3: fully thread-independent fused loss; in-block reduction.
__global__ __launch_bounds__(TPB) void ldr_loss(
    const float* __restrict__ pred, const float* __restrict__ targ,
    const float* __restrict__ cin,
    float amS, float amL, float* __restrict__ partial, int rows)
{
    __shared__ float rs[4];
    const int tid = blockIdx.x * TPB + threadIdx.x;
    const int lane = threadIdx.x & 63, w = threadIdx.x >> 6;
    const int r = tid >> 16, m = tid & (SEGS - 1);
    const int a = (m + MOFF) & (SEGS - 1);
    const int b = (m + MOFF + 1) & (SEGS - 1);
    const float* P = pred + (size_t)r * TLEN;
    const float* T = targ + (size_t)r * TLEN;
    const size_t plane = (size_t)rows * SEGS;
    const size_t rbase = (size_t)r * SEGS;

    float sp[SL], st[SL];
    {
        const float4* Sp4 = (const float4*)(P + (size_t)m * SL);
        const float4* St4 = (const float4*)(T + (size_t)m * SL);
        float ysp = cin[0 * plane + rbase + m];
        float yst = cin[1 * plane + rbase + m];
        #pragma unroll
        for (int q = 0; q < SL / 4; ++q) {
            float4 u = Sp4[q], v = St4[q];
            #pragma unroll
            for (int mm = 0; mm < 4; ++mm) {
                ysp = fmaf(amS, ysp, comp(u, mm)); sp[4 * q + mm] = ysp;
                yst = fmaf(amS, yst, comp(v, mm)); st[4 * q + mm] = yst;
            }
        }
    }

    float ylp = cin[2 * plane + rbase + a];
    float ylt = cin[3 * plane + rbase + a];
    const float4* Ap4 = (const float4*)(P + (size_t)a * SL);
    const float4* At4 = (const float4*)(T + (size_t)a * SL);
    const float4* Bp4 = (const float4*)(P + (size_t)b * SL);
    const float4* Bt4 = (const float4*)(T + (size_t)b * SL);

    float lsum = 0.f;
    #pragma unroll
    for (int q = 0; q < SL / 4; ++q) {
        float4 u = Ap4[q], v = At4[q];
        #pragma unroll
        for (int mm = 0; mm < 4; ++mm) {
            const int e = 4 * q + mm;
            ylp = fmaf(amL, ylp, comp(u, mm));
            ylt = fmaf(amL, ylt, comp(v, mm));
            if (e >= ROFF) {
                const int i = e - ROFF;
                lsum += fabsf(__logf(__fdividef(sp[i] * ylt, st[i] * ylp)));
            }
        }
    }
    #pragma unroll
    for (int q = 0; q < 2; ++q) {
        float4 u = Bp4[q], v = Bt4[q];
        #pragma unroll
        for (int mm = 0; mm < 4; ++mm) {
            const int e = 4 * q + mm;
            if (e < ROFF) {
                ylp = fmaf(amL, ylp, comp(u, mm));
                ylt = fmaf(amL, ylt, comp(v, mm));
                const int i = e + (SL - ROFF);
                lsum += fabsf(__logf(__fdividef(sp[i] * ylt, st[i] * ylp)));
            }
        }
    }

    #pragma unroll
    for (int d = 32; d > 0; d >>= 1) lsum += __shfl_xor(lsum, d, 64);
    if (lane == 0) rs[w] = lsum;
    __syncthreads();
    if (threadIdx.x == 0)
        partial[blockIdx.x] = rs[0] + rs[1] + rs[2] + rs[3];
}

__global__ void ldr_finalize(const float* __restrict__ partial, int nparts,
                             float* __restrict__ out, double inv_n)
{
    __shared__ double sd[256];
    double s = 0.0;
    for (int i = threadIdx.x; i < nparts; i += 256) s += (double)partial[i];
    sd[threadIdx.x] = s;
    __syncthreads();
    for (int d = 128; d > 0; d >>= 1) {
        if (threadIdx.x < d) sd[threadIdx.x] += sd[threadIdx.x + d];
        __syncthreads();
    }
    if (threadIdx.x == 0) out[0] = (float)(sd[0] * inv_n);
}

extern "C" void kernel_launch(void* const* d_in, const int* in_sizes, int n_in,
                              void* d_out, int out_size, void* d_ws, size_t ws_size,
                              hipStream_t stream)
{
    const float* pred = (const float*)d_in[0];
    const float* targ = (const float*)d_in[1];
    const int n = in_sizes[0];
    const int rows = n / TLEN;   // 16

    const double csd = 1.0 - exp(-2200.0 / (50.0 * 44100.0));
    const double cld = 1.0 - exp(-2200.0 / (3000.0 * 44100.0));
    const double amSd = 1.0 - csd, amLd = 1.0 - cld;
    const float amS = (float)amSd, amL = (float)amLd;
    const float AcS    = (float)pow(amSd, 16.0);       // per segment
    const float AcL    = (float)pow(amLd, 16.0);
    const float Ac256S = (float)pow(amSd, 16.0 * 256); // per 256 segments
    const float Ac256L = (float)pow(amLd, 16.0 * 256);
    const float AtS    = (float)pow(amSd, 16.0 * TILE); // per tile
    const float AtL    = (float)pow(amLd, 16.0 * TILE);

    // ws: [0,256) reserved; pB (NEMA*rows*SEGS floats = 16.8 MB; aggregates,
    // overwritten in-place with carry-ins by 2c); partial (4096 f);
    // tA (64*64 f); tC (64*64 f).
    char* wsb = (char*)d_ws;
    float* pB      = (float*)(wsb + 256);
    float* partial = pB + (size_t)NEMA * rows * SEGS;
    float* tA      = partial + 4096;
    float* tC      = tA + NEMA * 16 * NTILE;

    const int nthreads = rows * SEGS;              // 1048576
    const int nblocksL = nthreads / TPB;           // 4096 (loss)
    const int nblocksP = rows * PAIRS / TPB;       // 2048 (partials)
    const int nplanes  = NEMA * rows;              // 64

    ldr_partials<<<nblocksP, TPB, 0, stream>>>(pred, targ, amS, amL, pB, rows);
    dim3 gridT(NTILE, nplanes);
    ldr_tile_agg<<<gridT, TPB, 0, stream>>>(pB, tA, AcS, AcL, rows);
    ldr_tile_scan<<<nplanes, 64, 0, stream>>>(tA, tC, AtS, AtL, rows);
    ldr_carry_fill<<<gridT, TPB, 0, stream>>>(pB, tC, AcS, AcL,
                                              Ac256S, Ac256L, rows);
    ldr_loss<<<nblocksL, TPB, 0, stream>>>(pred, targ, pB, amS, amL,
                                           partial, rows);

    const double inv_n = 1.0 / ((double)rows * (double)TLEN);
    ldr_finalize<<<1, 256, 0, stream>>>(partial, nblocksL, (float*)d_out, inv_n);
}

// Round 14
// 80.199 us; speedup vs baseline: 1.3824x; 1.0018x over previous
//
#include <hip/hip_runtime.h>
#include <math.h>

#define TPB   256
#define SL    16             // per-segment length
#define SEGS  65536          // TLEN / SL (per row)
#define PAIRS 32768          // SEGS/2 (pass-1 thread = 2 segments)
#define TLEN  1048576
#define MOFF  4065           // 65047 / 16
#define ROFF  7              // 65047 % 16
#define NEMA  4              // 0: short/pred, 1: short/targ, 2: long/pred, 3: long/targ
#define TILE  1024           // segments per scan tile (256 threads * 4)
#define NTILE 64             // SEGS / TILE

typedef float v4f __attribute__((ext_vector_type(4)));

__device__ __forceinline__ float comp(const float4& v, int m) {
    return m == 0 ? v.x : m == 1 ? v.y : m == 2 ? v.z : v.w;
}

__device__ __forceinline__ float ipowf(float base, int e) {
    float r = 1.0f, p = base;
    while (e) { if (e & 1) r *= p; p *= p; e >>= 1; }
    return r;
}

// Pass 1: per-16-sample-segment UNSCALED EMA aggregates, 2 segments/thread.
// The 16 global_load_dwordx4 are ONE volatile asm block with early-clobber
// quad outputs: the allocator MUST keep 64 result VGPRs live and the HW MUST
// issue all 16 loads before the s_waitcnt -> 16 KB in flight per wave.
// (R7 pins / R12 memory-clobber / R13 sched_barrier all failed to force this;
// VGPR stayed <=40 and each thread had ~6 loads in flight.)
__global__ __launch_bounds__(TPB) void ldr_partials(
    const float* __restrict__ pred, const float* __restrict__ targ,
    float amS, float amL, float* __restrict__ pB, int rows)
{
    const int tid = blockIdx.x * TPB + threadIdx.x;
    const int r = tid / PAIRS;
    const int p = tid & (PAIRS - 1);
    const size_t base = (size_t)r * TLEN + (size_t)p * 32;
    const float* P = pred + base;
    const float* T = targ + base;

    v4f u0, u1, u2, u3, u4, u5, u6, u7;
    v4f w0, w1, w2, w3, w4, w5, w6, w7;
    asm volatile(
        "global_load_dwordx4 %[u0], %[pa], off\n\t"
        "global_load_dwordx4 %[u1], %[pa], off offset:16\n\t"
        "global_load_dwordx4 %[u2], %[pa], off offset:32\n\t"
        "global_load_dwordx4 %[u3], %[pa], off offset:48\n\t"
        "global_load_dwordx4 %[u4], %[pa], off offset:64\n\t"
        "global_load_dwordx4 %[u5], %[pa], off offset:80\n\t"
        "global_load_dwordx4 %[u6], %[pa], off offset:96\n\t"
        "global_load_dwordx4 %[u7], %[pa], off offset:112\n\t"
        "global_load_dwordx4 %[w0], %[ta], off\n\t"
        "global_load_dwordx4 %[w1], %[ta], off offset:16\n\t"
        "global_load_dwordx4 %[w2], %[ta], off offset:32\n\t"
        "global_load_dwordx4 %[w3], %[ta], off offset:48\n\t"
        "global_load_dwordx4 %[w4], %[ta], off offset:64\n\t"
        "global_load_dwordx4 %[w5], %[ta], off offset:80\n\t"
        "global_load_dwordx4 %[w6], %[ta], off offset:96\n\t"
        "global_load_dwordx4 %[w7], %[ta], off offset:112\n\t"
        "s_waitcnt vmcnt(0)"
        : [u0] "=&v"(u0), [u1] "=&v"(u1), [u2] "=&v"(u2), [u3] "=&v"(u3),
          [u4] "=&v"(u4), [u5] "=&v"(u5), [u6] "=&v"(u6), [u7] "=&v"(u7),
          [w0] "=&v"(w0), [w1] "=&v"(w1), [w2] "=&v"(w2), [w3] "=&v"(w3),
          [w4] "=&v"(w4), [w5] "=&v"(w5), [w6] "=&v"(w6), [w7] "=&v"(w7)
        : [pa] "v"(P), [ta] "v"(T)
        : "memory");

    float res[NEMA][2];
    #define PQ(Q) { sp = fmaf(amS, sp, Q.x); lp = fmaf(amL, lp, Q.x);         \
                    sp = fmaf(amS, sp, Q.y); lp = fmaf(amL, lp, Q.y);         \
                    sp = fmaf(amS, sp, Q.z); lp = fmaf(amL, lp, Q.z);         \
                    sp = fmaf(amS, sp, Q.w); lp = fmaf(amL, lp, Q.w); }
    #define TQ(Q) { st = fmaf(amS, st, Q.x); lt = fmaf(amL, lt, Q.x);         \
                    st = fmaf(amS, st, Q.y); lt = fmaf(amL, lt, Q.y);         \
                    st = fmaf(amS, st, Q.z); lt = fmaf(amL, lt, Q.z);         \
                    st = fmaf(amS, st, Q.w); lt = fmaf(amL, lt, Q.w); }
    {
        float sp = 0.f, st = 0.f, lp = 0.f, lt = 0.f;
        PQ(u0) PQ(u1) PQ(u2) PQ(u3)
        TQ(w0) TQ(w1) TQ(w2) TQ(w3)
        res[0][0] = sp; res[1][0] = st; res[2][0] = lp; res[3][0] = lt;
    }
    {
        float sp = 0.f, st = 0.f, lp = 0.f, lt = 0.f;
        PQ(u4) PQ(u5) PQ(u6) PQ(u7)
        TQ(w4) TQ(w5) TQ(w6) TQ(w7)
        res[0][1] = sp; res[1][1] = st; res[2][1] = lp; res[3][1] = lt;
    }
    #undef PQ
    #undef TQ
    const size_t plane = (size_t)rows * SEGS;
    const size_t idx = (size_t)r * SEGS + 2 * (size_t)p;
    #pragma unroll
    for (int E = 0; E < NEMA; ++E)
        *(float2*)(pB + E * plane + idx) = make_float2(res[E][0], res[E][1]);
}

// Pass 2a: per-tile (1024-segment) aggregates. Coalesced float4 reads.
__global__ __launch_bounds__(TPB) void ldr_tile_agg(
    const float* __restrict__ pB, float* __restrict__ tA,
    float AcS, float AcL, int rows)
{
    __shared__ float slots[4];
    const int t = blockIdx.x, g = blockIdx.y;
    const int j = threadIdx.x, lane = j & 63, w = j >> 6;
    const float Ac = (g < 2 * rows) ? AcS : AcL;       // am^SL
    const float Ac4 = (Ac * Ac) * (Ac * Ac);
    const float4 E = *(const float4*)(pB + (size_t)g * SEGS
                                      + (size_t)t * TILE + (size_t)j * 4);
    float B = E.x;
    B = fmaf(Ac, B, E.y); B = fmaf(Ac, B, E.z); B = fmaf(Ac, B, E.w);
    float incl = B, Ad = Ac4;
    #pragma unroll
    for (int d = 1; d < 64; d <<= 1) {
        float pb = __shfl_up(incl, d, 64);
        if (lane >= d) incl = fmaf(Ad, pb, incl);
        Ad *= Ad;
    }
    if (lane == 63) slots[w] = incl;
    __syncthreads();
    if (j == 0) {
        const float Ac256 = ipowf(Ac4, 64);
        float T = slots[0];
        T = fmaf(Ac256, T, slots[1]);
        T = fmaf(Ac256, T, slots[2]);
        T = fmaf(Ac256, T, slots[3]);
        tA[g * NTILE + t] = T;
    }
}

// Pass 2b: per-plane scan of the 64 tile aggregates -> tile carry-ins.
__global__ __launch_bounds__(64) void ldr_tile_scan(
    const float* __restrict__ tA, float* __restrict__ tC,
    float AtS, float AtL, int rows)
{
    const int g = blockIdx.x, lane = threadIdx.x;
    const float A = (g < 2 * rows) ? AtS : AtL;        // am^(SL*TILE)
    float incl = tA[g * NTILE + lane], Ad = A;
    #pragma unroll
    for (int d = 1; d < 64; d <<= 1) {
        float pb = __shfl_up(incl, d, 64);
        if (lane >= d) incl = fmaf(Ad, pb, incl);
        Ad *= Ad;
    }
    float ex = __shfl_up(incl, 1, 64);
    if (lane == 0) ex = 0.f;
    tC[g * NTILE + lane] = ex;
}

// Pass 2c: convert aggregates -> per-segment carry-ins, in place, coalesced.
__global__ __launch_bounds__(TPB) void ldr_carry_fill(
    float* __restrict__ pB, const float* __restrict__ tC,
    float AcS, float AcL, float Ac256S, float Ac256L, int rows)
{
    __shared__ float slots[4];
    const int t = blockIdx.x, g = blockIdx.y;
    const int j = threadIdx.x, lane = j & 63, w = j >> 6;
    const bool isShort = g < 2 * rows;
    const float Ac    = isShort ? AcS : AcL;
    const float Ac4   = (Ac * Ac) * (Ac * Ac);
    const float Ac256 = isShort ? Ac256S : Ac256L;     // am^(SL*256)
    float* ptr = pB + (size_t)g * SEGS + (size_t)t * TILE + (size_t)j * 4;
    const float4 E = *(const float4*)ptr;
    float B = E.x;
    B = fmaf(Ac, B, E.y); B = fmaf(Ac, B, E.z); B = fmaf(Ac, B, E.w);
    float incl = B, Ad = Ac4;
    #pragma unroll
    for (int d = 1; d < 64; d <<= 1) {
        float pb = __shfl_up(incl, d, 64);
        if (lane >= d) incl = fmaf(Ad, pb, incl);
        Ad *= Ad;
    }
    float ex = __shfl_up(incl, 1, 64);
    if (lane == 0) ex = 0.f;
    if (lane == 63) slots[w] = incl;
    __syncthreads();
    float acc = tC[g * NTILE + t];
    for (int u = 0; u < w; ++u) acc = fmaf(acc, Ac256, slots[u]);
    float carry = fmaf(ipowf(Ac4, lane), acc, ex);
    float4 out;
    out.x = carry; carry = fmaf(Ac, carry, E.x);
    out.y = carry; carry = fmaf(Ac, carry, E.y);
    out.z = carry; carry = fmaf(Ac, carry, E.z);
    out.w = carry;
    *(float4*)ptr = out;
}

// Pass 3: fully thread-independent fused loss; in-block reduction.
__global__ __launch_bounds__(TPB) void ldr_loss(
    const float* __restrict__ pred, const float* __restrict__ targ,
    const float* __restrict__ cin,
    float amS, float amL, float* __restrict__ partial, int rows)
{
    __shared__ float rs[4];
    const int tid = blockIdx.x * TPB + threadIdx.x;
    const int lane = threadIdx.x & 63, w = threadIdx.x >> 6;
    const int r = tid >> 16, m = tid & (SEGS - 1);
    const int a = (m + MOFF) & (SEGS - 1);
    const int b = (m + MOFF + 1) & (SEGS - 1);
    const float* P = pred + (size_t)r * TLEN;
    const float* T = targ + (size_t)r * TLEN;
    const size_t plane = (size_t)rows * SEGS;
    const size_t rbase = (size_t)r * SEGS;

    float sp[SL], st[SL];
    {
        const float4* Sp4 = (const float4*)(P + (size_t)m * SL);
        const float4* St4 = (const float4*)(T + (size_t)m * SL);
        float ysp = cin[0 * plane + rbase + m];
        float yst = cin[1 * plane + rbase + m];
        #pragma unroll
        for (int q = 0; q < SL / 4; ++q) {
            float4 u = Sp4[q], v = St4[q];
            #pragma unroll
            for (int mm = 0; mm < 4; ++mm) {
                ysp = fmaf(amS, ysp, comp(u, mm)); sp[4 * q + mm] = ysp;
                yst = fmaf(amS, yst, comp(v, mm)); st[4 * q + mm] = yst;
            }
        }
    }

    float ylp = cin[2 * plane + rbase + a];
    float ylt = cin[3 * plane + rbase + a];
    const float4* Ap4 = (const float4*)(P + (size_t)a * SL);
    const float4* At4 = (const float4*)(T + (size_t)a * SL);
    const float4* Bp4 = (const float4*)(P + (size_t)b * SL);
    const float4* Bt4 = (const float4*)(T + (size_t)b * SL);

    float lsum = 0.f;
    #pragma unroll
    for (int q = 0; q < SL / 4; ++q) {
        float4 u = Ap4[q], v = At4[q];
        #pragma unroll
        for (int mm = 0; mm < 4; ++mm) {
            const int e = 4 * q + mm;
            ylp = fmaf(amL, ylp, comp(u, mm));
            ylt = fmaf(amL, ylt, comp(v, mm));
            if (e >= ROFF) {
                const int i = e - ROFF;
                lsum += fabsf(__logf(__fdividef(sp[i] * ylt, st[i] * ylp)));
            }
        }
    }
    #pragma unroll
    for (int q = 0; q < 2; ++q) {
        float4 u = Bp4[q], v = Bt4[q];
        #pragma unroll
        for (int mm = 0; mm < 4; ++mm) {
            const int e = 4 * q + mm;
            if (e < ROFF) {
                ylp = fmaf(amL, ylp, comp(u, mm));
                ylt = fmaf(amL, ylt, comp(v, mm));
                const int i = e + (SL - ROFF);
                lsum += fabsf(__logf(__fdividef(sp[i] * ylt, st[i] * ylp)));
            }
        }
    }

    #pragma unroll
    for (int d = 32; d > 0; d >>= 1) lsum += __shfl_xor(lsum, d, 64);
    if (lane == 0) rs[w] = lsum;
    __syncthreads();
    if (threadIdx.x == 0)
        partial[blockIdx.x] = rs[0] + rs[1] + rs[2] + rs[3];
}

__global__ void ldr_finalize(const float* __restrict__ partial, int nparts,
                             float* __restrict__ out, double inv_n)
{
    __shared__ double sd[256];
    double s = 0.0;
    for (int i = threadIdx.x; i < nparts; i += 256) s += (double)partial[i];
    sd[threadIdx.x] = s;
    __syncthreads();
    for (int d = 128; d > 0; d >>= 1) {
        if (threadIdx.x < d) sd[threadIdx.x] += sd[threadIdx.x + d];
        __syncthreads();
    }
    if (threadIdx.x == 0) out[0] = (float)(sd[0] * inv_n);
}

extern "C" void kernel_launch(void* const* d_in, const int* in_sizes, int n_in,
                              void* d_out, int out_size, void* d_ws, size_t ws_size,
                              hipStream_t stream)
{
    const float* pred = (const float*)d_in[0];
    const float* targ = (const float*)d_in[1];
    const int n = in_sizes[0];
    const int rows = n / TLEN;   // 16

    const double csd = 1.0 - exp(-2200.0 / (50.0 * 44100.0));
    const double cld = 1.0 - exp(-2200.0 / (3000.0 * 44100.0));
    const double amSd = 1.0 - csd, amLd = 1.0 - cld;
    const float amS = (float)amSd, amL = (float)amLd;
    const float AcS    = (float)pow(amSd, 16.0);       // per segment
    const float AcL    = (float)pow(amLd, 16.0);
    const float Ac256S = (float)pow(amSd, 16.0 * 256); // per 256 segments
    const float Ac256L = (float)pow(amLd, 16.0 * 256);
    const float AtS    = (float)pow(amSd, 16.0 * TILE); // per tile
    const float AtL    = (float)pow(amLd, 16.0 * TILE);

    // ws: [0,256) reserved; pB (NEMA*rows*SEGS floats = 16.8 MB; aggregates,
    // overwritten in-place with carry-ins by 2c); partial (4096 f);
    // tA (64*64 f); tC (64*64 f).
    char* wsb = (char*)d_ws;
    float* pB      = (float*)(wsb + 256);
    float* partial = pB + (size_t)NEMA * rows * SEGS;
    float* tA      = partial + 4096;
    float* tC      = tA + NEMA * 16 * NTILE;

    const int nthreads = rows * SEGS;              // 1048576
    const int nblocksL = nthreads / TPB;           // 4096 (loss)
    const int nblocksP = rows * PAIRS / TPB;       // 2048 (partials)
    const int nplanes  = NEMA * rows;              // 64

    ldr_partials<<<nblocksP, TPB, 0, stream>>>(pred, targ, amS, amL, pB, rows);
    dim3 gridT(NTILE, nplanes);
    ldr_tile_agg<<<gridT, TPB, 0, stream>>>(pB, tA, AcS, AcL, rows);
    ldr_tile_scan<<<nplanes, 64, 0, stream>>>(tA, tC, AtS, AtL, rows);
    ldr_carry_fill<<<gridT, TPB, 0, stream>>>(pB, tC, AcS, AcL,
                                              Ac256S, Ac256L, rows);
    ldr_loss<<<nblocksL, TPB, 0, stream>>>(pred, targ, pB, amS, amL,
                                           partial, rows);

    const double inv_n = 1.0 / ((double)rows * (double)TLEN);
    ldr_finalize<<<1, 256, 0, stream>>>(partial, nblocksL, (float*)d_out, inv_n);
}

// Round 15
// 76.398 us; speedup vs baseline: 1.4511x; 1.0497x over previous
//
#include <hip/hip_runtime.h>
#include <math.h>

#define TPB   256
#define SL    16             // per-segment length
#define SEGS  65536          // segments per row
#define PAIRS 32768          // SEGS/2 (pass-1 thread = 2 segments)
#define TLEN  1048576
#define MOFF  4065           // 65047 / 16
#define ROFF  7              // 65047 % 16
#define NEMA  4              // 0: short/pred, 1: short/targ, 2: long/pred, 3: long/targ
#define TPL   256            // tiles per plane-row (SEGS / TILE), TILE = 256 segs

typedef float v4f __attribute__((ext_vector_type(4)));

__device__ __forceinline__ float comp(const float4& v, int m) {
    return m == 0 ? v.x : m == 1 ? v.y : m == 2 ? v.z : v.w;
}

__device__ __forceinline__ float ipowf(float base, int e) {
    float r = 1.0f, p = base;
    while (e) { if (e & 1) r *= p; p *= p; e >>= 1; }
    return r;
}

// Pass 1: per-16-sample-segment EMA aggregates (2 segs/thread, proven asm
// load block) + INLINE tile (256-seg) aggregates via weighted wave reduce:
// tileAgg = sum_h pairAgg_h * Ac32^(127-h)  (h = thread-in-tile).
__global__ __launch_bounds__(TPB) void ldr_partials(
    const float* __restrict__ pred, const float* __restrict__ targ,
    float amS, float amL, float Ac16S, float Ac16L,
    float* __restrict__ pB, float* __restrict__ tA, int rows)
{
    __shared__ float wt[4][NEMA];
    const int b = blockIdx.x, j = threadIdx.x;
    const int lane = j & 63, w = j >> 6;
    const int tid = b * TPB + j;
    const int r = tid >> 15;                  // PAIRS=32768 per row
    const int p = tid & (PAIRS - 1);
    const size_t base = (size_t)r * TLEN + (size_t)p * 32;
    const float* P = pred + base;
    const float* T = targ + base;

    v4f u0, u1, u2, u3, u4, u5, u6, u7;
    v4f w0, w1, w2, w3, w4, w5, w6, w7;
    asm volatile(
        "global_load_dwordx4 %[u0], %[pa], off\n\t"
        "global_load_dwordx4 %[u1], %[pa], off offset:16\n\t"
        "global_load_dwordx4 %[u2], %[pa], off offset:32\n\t"
        "global_load_dwordx4 %[u3], %[pa], off offset:48\n\t"
        "global_load_dwordx4 %[u4], %[pa], off offset:64\n\t"
        "global_load_dwordx4 %[u5], %[pa], off offset:80\n\t"
        "global_load_dwordx4 %[u6], %[pa], off offset:96\n\t"
        "global_load_dwordx4 %[u7], %[pa], off offset:112\n\t"
        "global_load_dwordx4 %[w0], %[ta], off\n\t"
        "global_load_dwordx4 %[w1], %[ta], off offset:16\n\t"
        "global_load_dwordx4 %[w2], %[ta], off offset:32\n\t"
        "global_load_dwordx4 %[w3], %[ta], off offset:48\n\t"
        "global_load_dwordx4 %[w4], %[ta], off offset:64\n\t"
        "global_load_dwordx4 %[w5], %[ta], off offset:80\n\t"
        "global_load_dwordx4 %[w6], %[ta], off offset:96\n\t"
        "global_load_dwordx4 %[w7], %[ta], off offset:112\n\t"
        "s_waitcnt vmcnt(0)"
        : [u0] "=&v"(u0), [u1] "=&v"(u1), [u2] "=&v"(u2), [u3] "=&v"(u3),
          [u4] "=&v"(u4), [u5] "=&v"(u5), [u6] "=&v"(u6), [u7] "=&v"(u7),
          [w0] "=&v"(w0), [w1] "=&v"(w1), [w2] "=&v"(w2), [w3] "=&v"(w3),
          [w4] "=&v"(w4), [w5] "=&v"(w5), [w6] "=&v"(w6), [w7] "=&v"(w7)
        : [pa] "v"(P), [ta] "v"(T)
        : "memory");

    float res[NEMA][2];
    #define PQ(Q) { sp = fmaf(amS, sp, Q.x); lp = fmaf(amL, lp, Q.x);         \
                    sp = fmaf(amS, sp, Q.y); lp = fmaf(amL, lp, Q.y);         \
                    sp = fmaf(amS, sp, Q.z); lp = fmaf(amL, lp, Q.z);         \
                    sp = fmaf(amS, sp, Q.w); lp = fmaf(amL, lp, Q.w); }
    #define TQ(Q) { st = fmaf(amS, st, Q.x); lt = fmaf(amL, lt, Q.x);         \
                    st = fmaf(amS, st, Q.y); lt = fmaf(amL, lt, Q.y);         \
                    st = fmaf(amS, st, Q.z); lt = fmaf(amL, lt, Q.z);         \
                    st = fmaf(amS, st, Q.w); lt = fmaf(amL, lt, Q.w); }
    {
        float sp = 0.f, st = 0.f, lp = 0.f, lt = 0.f;
        PQ(u0) PQ(u1) PQ(u2) PQ(u3)
        TQ(w0) TQ(w1) TQ(w2) TQ(w3)
        res[0][0] = sp; res[1][0] = st; res[2][0] = lp; res[3][0] = lt;
    }
    {
        float sp = 0.f, st = 0.f, lp = 0.f, lt = 0.f;
        PQ(u4) PQ(u5) PQ(u6) PQ(u7)
        TQ(w4) TQ(w5) TQ(w6) TQ(w7)
        res[0][1] = sp; res[1][1] = st; res[2][1] = lp; res[3][1] = lt;
    }
    #undef PQ
    #undef TQ
    const size_t plane = (size_t)rows * SEGS;
    const size_t idx = (size_t)r * SEGS + 2 * (size_t)p;
    #pragma unroll
    for (int E = 0; E < NEMA; ++E)
        *(float2*)(pB + E * plane + idx) = make_float2(res[E][0], res[E][1]);

    // tile aggregates: pairAgg = Ac16*res0 + res1, weight Ac32^(127-h)
    const int h = j & 127;
    const float Ac32S = Ac16S * Ac16S, Ac32L = Ac16L * Ac16L;
    const float wgtS = ipowf(Ac32S, 127 - h);
    const float wgtL = ipowf(Ac32L, 127 - h);
    #pragma unroll
    for (int E = 0; E < NEMA; ++E) {
        const float Ac16 = (E < 2) ? Ac16S : Ac16L;
        const float wgt  = (E < 2) ? wgtS : wgtL;
        float c = fmaf(Ac16, res[E][0], res[E][1]) * wgt;
        #pragma unroll
        for (int d = 32; d > 0; d >>= 1) c += __shfl_xor(c, d, 64);
        if (lane == 0) wt[w][E] = c;
    }
    __syncthreads();
    if (j == 0) {
        const int lt0 = (b & 127) << 1;       // 128 blocks/row -> 2 tiles each
        #pragma unroll
        for (int E = 0; E < NEMA; ++E) {
            float* tp = tA + ((size_t)E * rows + r) * TPL;
            tp[lt0]     = wt[0][E] + wt[1][E];
            tp[lt0 + 1] = wt[2][E] + wt[3][E];
        }
    }
}

// Pass 2: scan 256 tile aggregates per plane -> tile carry-ins. 64 blocks.
__global__ __launch_bounds__(64) void ldr_tile_scan(
    const float* __restrict__ tA, float* __restrict__ tC,
    float AcT_S, float AcT_L, int rows)
{
    const int g = blockIdx.x, lane = threadIdx.x;
    const float AcT = (g < 2 * rows) ? AcT_S : AcT_L;    // am^4096 per tile
    const float AcT4 = ((AcT * AcT) * (AcT * AcT));
    const float* Bv = tA + (size_t)g * TPL + lane * 4;
    float b4[4];
    float B = 0.f;
    #pragma unroll
    for (int m = 0; m < 4; ++m) { b4[m] = Bv[m]; B = fmaf(AcT, B, b4[m]); }
    float incl = B, Ad = AcT4;
    #pragma unroll
    for (int d = 1; d < 64; d <<= 1) {
        float pb = __shfl_up(incl, d, 64);
        if (lane >= d) incl = fmaf(Ad, pb, incl);
        Ad *= Ad;
    }
    float carry = __shfl_up(incl, 1, 64);
    if (lane == 0) carry = 0.f;
    float* co = tC + (size_t)g * TPL + lane * 4;
    #pragma unroll
    for (int m = 0; m < 4; ++m) {
        co[m] = carry;
        carry = fmaf(AcT, carry, b4[m]);
    }
}

// Pass 3: fused loss. Block b covers tile bl = b&255 of row r = b>>8
// (256 consecutive segments). Phase A derives per-thread carries in-block:
//   short: scan own tile (1 seg/thread) from tC base.
//   long:  scan tiles bl+15 (threads 0..127) and bl+16 (threads 128..255),
//          2 segs/thread, carries exchanged via LDS; thread j needs span
//          offset 225+j (since 4065 = 15*256 + 225).
// Phase B: the proven per-thread loss body.
__global__ __launch_bounds__(TPB) void ldr_loss(
    const float* __restrict__ pred, const float* __restrict__ targ,
    const float* __restrict__ pB, const float* __restrict__ tC,
    float amS, float amL, float Ac16S, float Ac16L,
    float* __restrict__ partial, int rows)
{
    __shared__ float sS[2][4], sL[2][4];
    __shared__ float longC[2][512];
    __shared__ float rs[4];
    const int bgl = blockIdx.x;
    const int r = bgl >> 8, bl = bgl & 255;
    const int j = threadIdx.x, lane = j & 63, w = j >> 6;
    const int m = bl * 256 + j;                       // own seg (row-local)
    const size_t plane = (size_t)rows * SEGS;
    const size_t rbase = (size_t)r * SEGS;

    // ---- Phase A: short carries (own tile) ----
    const float A1024S = ipowf(Ac16S, 64);
    const float aLaneS = ipowf(Ac16S, lane);
    float aggS[2];
    aggS[0] = pB[0 * plane + rbase + m];
    aggS[1] = pB[1 * plane + rbase + m];
    float inS0 = aggS[0], inS1 = aggS[1], Ad = Ac16S;
    #pragma unroll
    for (int d = 1; d < 64; d <<= 1) {
        float p0 = __shfl_up(inS0, d, 64);
        float p1 = __shfl_up(inS1, d, 64);
        if (lane >= d) { inS0 = fmaf(Ad, p0, inS0); inS1 = fmaf(Ad, p1, inS1); }
        Ad *= Ad;
    }
    float exS0 = __shfl_up(inS0, 1, 64), exS1 = __shfl_up(inS1, 1, 64);
    if (lane == 0) { exS0 = 0.f; exS1 = 0.f; }
    if (lane == 63) { sS[0][w] = inS0; sS[1][w] = inS1; }

    // ---- Phase A: long carries (tiles bl+15, bl+16), 2 segs/thread ----
    const int half = j >> 7;                          // 0: tile bl+15, 1: bl+16
    const int hh = j & 127;
    const int tsel = (bl + 15 + half) & 255;
    const float Ac32L = Ac16L * Ac16L;
    const float A2048L = ipowf(Ac32L, 64);
    const float aLaneL = ipowf(Ac32L, lane);
    float2 agL0 = *(const float2*)(pB + 2 * plane + rbase + tsel * 256 + 2 * hh);
    float2 agL1 = *(const float2*)(pB + 3 * plane + rbase + tsel * 256 + 2 * hh);
    float pa0 = fmaf(Ac16L, agL0.x, agL0.y);
    float pa1 = fmaf(Ac16L, agL1.x, agL1.y);
    float inL0 = pa0, inL1 = pa1;
    Ad = Ac32L;
    #pragma unroll
    for (int d = 1; d < 64; d <<= 1) {
        float p0 = __shfl_up(inL0, d, 64);
        float p1 = __shfl_up(inL1, d, 64);
        if (lane >= d) { inL0 = fmaf(Ad, p0, inL0); inL1 = fmaf(Ad, p1, inL1); }
        Ad *= Ad;
    }
    float exL0 = __shfl_up(inL0, 1, 64), exL1 = __shfl_up(inL1, 1, 64);
    if (lane == 0) { exL0 = 0.f; exL1 = 0.f; }
    if (lane == 63) { sL[0][w] = inL0; sL[1][w] = inL1; }
    __syncthreads();

    // short: combine waves + tile base
    {
        const float baseS0 = tC[((size_t)0 * rows + r) * TPL + bl];
        const float baseS1 = tC[((size_t)1 * rows + r) * TPL + bl];
        float Wc0 = 0.f, Wc1 = 0.f;
        for (int u = 0; u < w; ++u) {
            Wc0 = fmaf(Wc0, A1024S, sS[0][u]);
            Wc1 = fmaf(Wc1, A1024S, sS[1][u]);
        }
        const float aThS = aLaneS * ipowf(A1024S, w);
        exS0 = fmaf(aThS, baseS0, fmaf(aLaneS, Wc0, exS0));  // short carry @m
        exS1 = fmaf(aThS, baseS1, fmaf(aLaneS, Wc1, exS1));
    }
    // long: combine within half + tile base, write both seg carries to LDS
    {
        const float baseL0 = tC[((size_t)2 * rows + r) * TPL + tsel];
        const float baseL1 = tC[((size_t)3 * rows + r) * TPL + tsel];
        const int hw = w & 1, fw = w & 2;
        float Wc0 = hw ? sL[0][fw] : 0.f;
        float Wc1 = hw ? sL[1][fw] : 0.f;
        const float aThL = aLaneL * (hw ? A2048L : 1.f);
        float c00 = fmaf(aThL, baseL0, fmaf(aLaneL, Wc0, exL0));
        float c10 = fmaf(aThL, baseL1, fmaf(aLaneL, Wc1, exL1));
        const int i0 = half * 256 + 2 * hh;
        longC[0][i0] = c00; longC[0][i0 + 1] = fmaf(Ac16L, c00, agL0.x);
        longC[1][i0] = c10; longC[1][i0 + 1] = fmaf(Ac16L, c10, agL1.x);
    }
    __syncthreads();
    const float cSp = exS0, cSt = exS1;
    const float cLp = longC[0][225 + j];
    const float cLt = longC[1][225 + j];

    // ---- Phase B: proven loss body ----
    const int a = (m + MOFF) & (SEGS - 1);
    const int bseg = (m + MOFF + 1) & (SEGS - 1);
    const float* P = pred + (size_t)r * TLEN;
    const float* T = targ + (size_t)r * TLEN;

    float sp[SL], st[SL];
    {
        const float4* Sp4 = (const float4*)(P + (size_t)m * SL);
        const float4* St4 = (const float4*)(T + (size_t)m * SL);
        float ysp = cSp, yst = cSt;
        #pragma unroll
        for (int q = 0; q < SL / 4; ++q) {
            float4 u = Sp4[q], v = St4[q];
            #pragma unroll
            for (int mm = 0; mm < 4; ++mm) {
                ysp = fmaf(amS, ysp, comp(u, mm)); sp[4 * q + mm] = ysp;
                yst = fmaf(amS, yst, comp(v, mm)); st[4 * q + mm] = yst;
            }
        }
    }
    float ylp = cLp, ylt = cLt;
    const float4* Ap4 = (const float4*)(P + (size_t)a * SL);
    const float4* At4 = (const float4*)(T + (size_t)a * SL);
    const float4* Bp4 = (const float4*)(P + (size_t)bseg * SL);
    const float4* Bt4 = (const float4*)(T + (size_t)bseg * SL);

    float lsum = 0.f;
    #pragma unroll
    for (int q = 0; q < SL / 4; ++q) {
        float4 u = Ap4[q], v = At4[q];
        #pragma unroll
        for (int mm = 0; mm < 4; ++mm) {
            const int e = 4 * q + mm;
            ylp = fmaf(amL, ylp, comp(u, mm));
            ylt = fmaf(amL, ylt, comp(v, mm));
            if (e >= ROFF) {
                const int i = e - ROFF;
                lsum += fabsf(__logf(__fdividef(sp[i] * ylt, st[i] * ylp)));
            }
        }
    }
    #pragma unroll
    for (int q = 0; q < 2; ++q) {
        float4 u = Bp4[q], v = Bt4[q];
        #pragma unroll
        for (int mm = 0; mm < 4; ++mm) {
            const int e = 4 * q + mm;
            if (e < ROFF) {
                ylp = fmaf(amL, ylp, comp(u, mm));
                ylt = fmaf(amL, ylt, comp(v, mm));
                const int i = e + (SL - ROFF);
                lsum += fabsf(__logf(__fdividef(sp[i] * ylt, st[i] * ylp)));
            }
        }
    }

    #pragma unroll
    for (int d = 32; d > 0; d >>= 1) lsum += __shfl_xor(lsum, d, 64);
    if (lane == 0) rs[w] = lsum;
    __syncthreads();
    if (j == 0) partial[bgl] = rs[0] + rs[1] + rs[2] + rs[3];
}

__global__ void ldr_finalize(const float* __restrict__ partial, int nparts,
                             float* __restrict__ out, double inv_n)
{
    __shared__ double sd[256];
    double s = 0.0;
    for (int i = threadIdx.x; i < nparts; i += 256) s += (double)partial[i];
    sd[threadIdx.x] = s;
    __syncthreads();
    for (int d = 128; d > 0; d >>= 1) {
        if (threadIdx.x < d) sd[threadIdx.x] += sd[threadIdx.x + d];
        __syncthreads();
    }
    if (threadIdx.x == 0) out[0] = (float)(sd[0] * inv_n);
}

extern "C" void kernel_launch(void* const* d_in, const int* in_sizes, int n_in,
                              void* d_out, int out_size, void* d_ws, size_t ws_size,
                              hipStream_t stream)
{
    const float* pred = (const float*)d_in[0];
    const float* targ = (const float*)d_in[1];
    const int n = in_sizes[0];
    const int rows = n / TLEN;   // 16

    const double csd = 1.0 - exp(-2200.0 / (50.0 * 44100.0));
    const double cld = 1.0 - exp(-2200.0 / (3000.0 * 44100.0));
    const double amSd = 1.0 - csd, amLd = 1.0 - cld;
    const float amS = (float)amSd, amL = (float)amLd;
    const float Ac16S = (float)pow(amSd, 16.0);
    const float Ac16L = (float)pow(amLd, 16.0);
    const float AcT_S = (float)pow(amSd, 4096.0);   // per 256-seg tile
    const float AcT_L = (float)pow(amLd, 4096.0);

    // ws: [0,256) reserved; pB (NEMA*rows*SEGS floats = 16.8 MB, read-only
    // aggregates); tA, tC (NEMA*rows*TPL floats = 64 KB each); partial.
    char* wsb = (char*)d_ws;
    float* pB      = (float*)(wsb + 256);
    float* tA      = pB + (size_t)NEMA * rows * SEGS;
    float* tC      = tA + (size_t)NEMA * rows * TPL;
    float* partial = tC + (size_t)NEMA * rows * TPL;

    const int nblocksP = rows * PAIRS / TPB;       // 2048
    const int nblocksL = rows * TPL;               // 4096
    const int nplanes  = NEMA * rows;              // 64

    ldr_partials<<<nblocksP, TPB, 0, stream>>>(pred, targ, amS, amL,
                                               Ac16S, Ac16L, pB, tA, rows);
    ldr_tile_scan<<<nplanes, 64, 0, stream>>>(tA, tC, AcT_S, AcT_L, rows);
    ldr_loss<<<nblocksL, TPB, 0, stream>>>(pred, targ, pB, tC, amS, amL,
                                           Ac16S, Ac16L, partial, rows);

    const double inv_n = 1.0 / ((double)rows * (double)TLEN);
    ldr_finalize<<<1, 256, 0, stream>>>(partial, nblocksL, (float*)d_out, inv_n);
}